// Round 1
// baseline (428.045 us; speedup 1.0000x reference)
//
#include <hip/hip_runtime.h>

typedef unsigned short u16;
typedef __attribute__((ext_vector_type(4))) float f32x4;
typedef __attribute__((ext_vector_type(8))) short bf16x8;

#define SEQ 2048
#define DM 1024
#define DKK 64
#define NH 16
#define DFF 2048
#define TOK 4096

#define AS1 __attribute__((address_space(1)))
#define AS3 __attribute__((address_space(3)))

#define MFMA16(a, b, c) __builtin_amdgcn_mfma_f32_16x16x32_bf16((a), (b), (c), 0, 0, 0)

__device__ __forceinline__ u16 f2b(float f) {
  unsigned u = __float_as_uint(f);
  u = u + 0x7fffu + ((u >> 16) & 1u);
  return (u16)(u >> 16);
}

__device__ __forceinline__ void gload_lds16(const u16* g, u16* l) {
  __builtin_amdgcn_global_load_lds((AS1 unsigned*)(size_t)g, (AS3 unsigned*)l, 16, 0, 0);
}

// ---------------- weight fp32 [K,N] -> bf16 [N,K] ----------------
__global__ __launch_bounds__(256)
void transpose_cvt(const float* __restrict__ W, u16* __restrict__ Wt, int K, int N) {
  __shared__ float t[32][33];
  const int n0 = blockIdx.x * 32, k0 = blockIdx.y * 32;
  const int tx = threadIdx.x, ty = threadIdx.y;
#pragma unroll
  for (int i = 0; i < 4; i++) {
    int k = ty + i * 8;
    t[k][tx] = W[(size_t)(k0 + k) * N + n0 + tx];
  }
  __syncthreads();
#pragma unroll
  for (int i = 0; i < 4; i++) {
    int n = ty + i * 8;
    Wt[(size_t)(n0 + n) * K + k0 + tx] = f2b(t[tx][n]);
  }
}

// ---------------- LayerNorm (ddof=1, alpha*(x-m)/(sqrt(var)+eps)+beta) -> bf16 ----------------
__global__ __launch_bounds__(256)
void ln_kernel(const float* __restrict__ x, const float* __restrict__ alpha,
               const float* __restrict__ beta, u16* __restrict__ out) {
  const int row = blockIdx.x;
  const float4 v = ((const float4*)(x + (size_t)row * DM))[threadIdx.x];
  float s = v.x + v.y + v.z + v.w;
  float q = v.x * v.x + v.y * v.y + v.z * v.z + v.w * v.w;
#pragma unroll
  for (int off = 1; off < 64; off <<= 1) {
    s += __shfl_xor(s, off);
    q += __shfl_xor(q, off);
  }
  __shared__ float ss[4], qq[4];
  const int wid = threadIdx.x >> 6;
  if ((threadIdx.x & 63) == 0) { ss[wid] = s; qq[wid] = q; }
  __syncthreads();
  s = ss[0] + ss[1] + ss[2] + ss[3];
  q = qq[0] + qq[1] + qq[2] + qq[3];
  const float mean = s * (1.f / DM);
  float var = (q - (float)DM * mean * mean) * (1.f / (DM - 1));
  var = fmaxf(var, 0.f);
  const float inv = 1.f / (sqrtf(var) + 1e-6f);
  const float4 a4 = ((const float4*)alpha)[threadIdx.x];
  const float4 b4 = ((const float4*)beta)[threadIdx.x];
  ushort4 o;
  o.x = f2b((v.x - mean) * inv * a4.x + b4.x);
  o.y = f2b((v.y - mean) * inv * a4.y + b4.y);
  o.z = f2b((v.z - mean) * inv * a4.z + b4.z);
  o.w = f2b((v.w - mean) * inv * a4.w + b4.w);
  ((ushort4*)(out + (size_t)row * DM))[threadIdx.x] = o;
}

// ---------------- GEMM: C[M,N] = A[M,K](bf16,row) @ Bt[N,K](bf16,row)^T ----------------
// MODE: 0 = QKV scatter to [B,H,S,dk] bf16; 1 = VT scatter to [B,H,dk,S] bf16 (A=W^T, B=x2);
//       2 = fp32 out = res + acc + bias;   3 = bf16 out = relu(acc + bias)
template <int MODE>
__global__ __launch_bounds__(256, 2)
void gemm_bt(const u16* __restrict__ A, const u16* __restrict__ Bt,
             int M, int N, int K,
             const float* __restrict__ bias, const float* __restrict__ res,
             void* __restrict__ outp) {
  __shared__ alignas(16) u16 As[128 * 32];
  __shared__ alignas(16) u16 Bs[128 * 32];
  const int bm = blockIdx.x * 128, bn = blockIdx.y * 128;
  const int tid = threadIdx.x;
  const int lane = tid & 63, w = tid >> 6;
  const int wm = (w >> 1) * 64, wn = (w & 1) * 64;
  const int r = lane & 15, g = lane >> 4;
  const int srow = tid >> 2, skk = (tid & 3) * 8;

  f32x4 acc[4][4];
#pragma unroll
  for (int i = 0; i < 4; i++)
#pragma unroll
    for (int j = 0; j < 4; j++) acc[i][j] = (f32x4){0.f, 0.f, 0.f, 0.f};

  const u16* a0 = A + (size_t)(bm + srow) * K + skk;
  const u16* a1 = A + (size_t)(bm + 64 + srow) * K + skk;
  const u16* b0 = Bt + (size_t)(bn + srow) * K + skk;
  const u16* b1 = Bt + (size_t)(bn + 64 + srow) * K + skk;
  u16* lA = As + w * 512;   // wave-uniform LDS base; HW adds lane*16B
  u16* lB = Bs + w * 512;

  for (int kt = 0; kt < K; kt += 32) {
    gload_lds16(a0 + kt, lA);
    gload_lds16(a1 + kt, lA + 2048);
    gload_lds16(b0 + kt, lB);
    gload_lds16(b1 + kt, lB + 2048);
    __syncthreads();
    bf16x8 af[4], bfr[4];
#pragma unroll
    for (int i = 0; i < 4; i++) af[i] = *(const bf16x8*)(As + (wm + i * 16 + r) * 32 + g * 8);
#pragma unroll
    for (int i = 0; i < 4; i++) bfr[i] = *(const bf16x8*)(Bs + (wn + i * 16 + r) * 32 + g * 8);
#pragma unroll
    for (int i = 0; i < 4; i++)
#pragma unroll
      for (int j = 0; j < 4; j++) acc[i][j] = MFMA16(af[i], bfr[j], acc[i][j]);
    __syncthreads();
  }

#pragma unroll
  for (int i = 0; i < 4; i++)
#pragma unroll
    for (int j = 0; j < 4; j++)
#pragma unroll
      for (int t = 0; t < 4; t++) {
        const int mg = bm + wm + i * 16 + g * 4 + t;
        const int ng = bn + wn + j * 16 + r;
        const float v = acc[i][j][t];
        if (MODE == 0) {  // token mg -> (b,s); col ng -> (h,d)
          const int bb = mg >> 11, ssx = mg & 2047, hh = ng >> 6, dd = ng & 63;
          ((u16*)outp)[((size_t)(bb * NH + hh) * SEQ + ssx) * DKK + dd] = f2b(v);
        } else if (MODE == 1) {  // row mg -> (h,d); col ng -> token (b,s)
          const int hh = mg >> 6, dd = mg & 63, bb = ng >> 11, ssx = ng & 2047;
          ((u16*)outp)[((size_t)(bb * NH + hh) * DKK + dd) * SEQ + ssx] = f2b(v);
        } else if (MODE == 2) {
          ((float*)outp)[(size_t)mg * N + ng] = res[(size_t)mg * N + ng] + v + bias[ng];
        } else {
          const float hv = v + bias[ng];
          ((u16*)outp)[(size_t)mg * N + ng] = f2b(hv > 0.f ? hv : 0.f);
        }
      }
}

// ---------------- flash attention: Q,K [B,H,S,dk] bf16; Vt [B,H,dk,S] bf16 ----------------
__global__ __launch_bounds__(256, 2)
void attn_kernel(const u16* __restrict__ Q, const u16* __restrict__ Kb,
                 const u16* __restrict__ Vt, const float* __restrict__ mask,
                 u16* __restrict__ outc) {
  const int qt = blockIdx.x, bh = blockIdx.y;
  const int b = bh >> 4, h = bh & 15;
  const int tid = threadIdx.x, lane = tid & 63, w = tid >> 6;
  const int r = lane & 15, g = lane >> 4;
  const int qbase = qt * 64 + w * 16;
  const u16* Qp = Q + ((size_t)bh * SEQ + qbase) * DKK;
  const u16* Kp = Kb + (size_t)bh * SEQ * DKK;
  const u16* Vp = Vt + (size_t)bh * DKK * SEQ;
  const float* mk = mask + b * SEQ;

  const bf16x8 aq0 = *(const bf16x8*)(Qp + r * DKK + g * 8);
  const bf16x8 aq1 = *(const bf16x8*)(Qp + r * DKK + 32 + g * 8);

  f32x4 o[4];
#pragma unroll
  for (int i = 0; i < 4; i++) o[i] = (f32x4){0.f, 0.f, 0.f, 0.f};
  float mr[4] = {-1e30f, -1e30f, -1e30f, -1e30f};
  float lr[4] = {0.f, 0.f, 0.f, 0.f};

  __shared__ alignas(16) u16 Plds[4][512];  // per-wave 16x32 bf16

  for (int sk = 0; sk < SEQ; sk += 32) {
    f32x4 s0 = (f32x4){0.f, 0.f, 0.f, 0.f};
    f32x4 s1 = (f32x4){0.f, 0.f, 0.f, 0.f};
    const u16* K0 = Kp + (size_t)(sk + r) * DKK;
    const u16* K1 = K0 + 16 * DKK;
    s0 = MFMA16(aq0, *(const bf16x8*)(K0 + g * 8), s0);
    s0 = MFMA16(aq1, *(const bf16x8*)(K0 + 32 + g * 8), s0);
    s1 = MFMA16(aq0, *(const bf16x8*)(K1 + g * 8), s1);
    s1 = MFMA16(aq1, *(const bf16x8*)(K1 + 32 + g * 8), s1);
    const float mk0 = mk[sk + r], mk1 = mk[sk + 16 + r];
    float p0[4], p1[4];
#pragma unroll
    for (int t = 0; t < 4; t++) {
      float v0 = s0[t] * 0.125f * mk0;
      float v1 = s1[t] * 0.125f * mk1;
      v0 = (v0 == 0.f) ? -1e30f : v0;   // masked_fill(attn==0, -inf)
      v1 = (v1 == 0.f) ? -1e30f : v1;
      p0[t] = v0;
      p1[t] = v1;
    }
#pragma unroll
    for (int t = 0; t < 4; t++) {
      float tm = fmaxf(p0[t], p1[t]);
      tm = fmaxf(tm, __shfl_xor(tm, 1));
      tm = fmaxf(tm, __shfl_xor(tm, 2));
      tm = fmaxf(tm, __shfl_xor(tm, 4));
      tm = fmaxf(tm, __shfl_xor(tm, 8));
      const float mnew = fmaxf(mr[t], tm);
      const float sf = __expf(mr[t] - mnew);
      const float e0 = __expf(p0[t] - mnew);
      const float e1 = __expf(p1[t] - mnew);
      float rs = e0 + e1;
      rs += __shfl_xor(rs, 1);
      rs += __shfl_xor(rs, 2);
      rs += __shfl_xor(rs, 4);
      rs += __shfl_xor(rs, 8);
      lr[t] = lr[t] * sf + rs;
      mr[t] = mnew;
      o[0][t] *= sf; o[1][t] *= sf; o[2][t] *= sf; o[3][t] *= sf;
      p0[t] = e0;
      p1[t] = e1;
    }
    __syncthreads();
#pragma unroll
    for (int t = 0; t < 4; t++) {
      Plds[w][(g * 4 + t) * 32 + r] = f2b(p0[t]);
      Plds[w][(g * 4 + t) * 32 + 16 + r] = f2b(p1[t]);
    }
    __syncthreads();
    const bf16x8 pa = *(const bf16x8*)(&Plds[w][r * 32 + g * 8]);
#pragma unroll
    for (int dc = 0; dc < 4; dc++) {
      const bf16x8 bv = *(const bf16x8*)(Vp + (size_t)(dc * 16 + r) * SEQ + sk + g * 8);
      o[dc] = MFMA16(pa, bv, o[dc]);
    }
  }
#pragma unroll
  for (int dc = 0; dc < 4; dc++)
#pragma unroll
    for (int t = 0; t < 4; t++) {
      const int srow_g = qbase + g * 4 + t;
      outc[((size_t)(b * SEQ + srow_g)) * DM + h * DKK + dc * 16 + r] = f2b(o[dc][t] / lr[t]);
    }
}

extern "C" void kernel_launch(void* const* d_in, const int* in_sizes, int n_in,
                              void* d_out, int out_size, void* d_ws, size_t ws_size,
                              hipStream_t stream) {
  const float* x    = (const float*)d_in[0];
  const float* mask = (const float*)d_in[1];
  const float* Wq   = (const float*)d_in[2];
  const float* Wk   = (const float*)d_in[3];
  const float* Wv   = (const float*)d_in[4];
  const float* Wo   = (const float*)d_in[5];
  const float* bo   = (const float*)d_in[6];
  const float* W1   = (const float*)d_in[7];
  const float* b1   = (const float*)d_in[8];
  const float* W2   = (const float*)d_in[9];
  const float* b2   = (const float*)d_in[10];
  const float* l1a  = (const float*)d_in[11];
  const float* l1b  = (const float*)d_in[12];
  const float* l2a  = (const float*)d_in[13];
  const float* l2b  = (const float*)d_in[14];

  char* wsb = (char*)d_ws;
  u16* Wqt = (u16*)(wsb + (0ull << 20));
  u16* Wkt = (u16*)(wsb + (2ull << 20));
  u16* Wvt = (u16*)(wsb + (4ull << 20));
  u16* Wot = (u16*)(wsb + (6ull << 20));
  u16* W1t = (u16*)(wsb + (8ull << 20));
  u16* W2t = (u16*)(wsb + (12ull << 20));
  u16* x2  = (u16*)(wsb + (16ull << 20));   // later reused as concat
  u16* qb  = (u16*)(wsb + (24ull << 20));   // later reused as x2b
  u16* kbf = (u16*)(wsb + (32ull << 20));   // later reused as h (with vtb)
  u16* vtb = (u16*)(wsb + (40ull << 20));
  float* x1 = (float*)(wsb + (48ull << 20));
  u16* concat = x2;
  u16* x2b = qb;
  u16* hb = kbf;  // 16MB spanning kbf..vtb

  const dim3 tb(32, 8);
  transpose_cvt<<<dim3(DM / 32, DM / 32), tb, 0, stream>>>(Wq, Wqt, DM, DM);
  transpose_cvt<<<dim3(DM / 32, DM / 32), tb, 0, stream>>>(Wk, Wkt, DM, DM);
  transpose_cvt<<<dim3(DM / 32, DM / 32), tb, 0, stream>>>(Wv, Wvt, DM, DM);
  transpose_cvt<<<dim3(DM / 32, DM / 32), tb, 0, stream>>>(Wo, Wot, DM, DM);
  transpose_cvt<<<dim3(DFF / 32, DM / 32), tb, 0, stream>>>(W1, W1t, DM, DFF);
  transpose_cvt<<<dim3(DM / 32, DFF / 32), tb, 0, stream>>>(W2, W2t, DFF, DM);

  ln_kernel<<<TOK, 256, 0, stream>>>(x, l1a, l1b, x2);

  gemm_bt<0><<<dim3(TOK / 128, DM / 128), 256, 0, stream>>>(x2, Wqt, TOK, DM, DM, nullptr, nullptr, qb);
  gemm_bt<0><<<dim3(TOK / 128, DM / 128), 256, 0, stream>>>(x2, Wkt, TOK, DM, DM, nullptr, nullptr, kbf);
  gemm_bt<1><<<dim3(DM / 128, TOK / 128), 256, 0, stream>>>(Wvt, x2, DM, TOK, DM, nullptr, nullptr, vtb);

  attn_kernel<<<dim3(SEQ / 64, 32), 256, 0, stream>>>(qb, kbf, vtb, mask, concat);

  gemm_bt<2><<<dim3(TOK / 128, DM / 128), 256, 0, stream>>>(concat, Wot, TOK, DM, DM, bo, x, x1);

  ln_kernel<<<TOK, 256, 0, stream>>>(x1, l2a, l2b, x2b);

  gemm_bt<3><<<dim3(TOK / 128, DFF / 128), 256, 0, stream>>>(x2b, W1t, TOK, DFF, DM, b1, nullptr, hb);
  gemm_bt<2><<<dim3(TOK / 128, DM / 128), 256, 0, stream>>>(hb, W2t, TOK, DM, DFF, b2, x1, (float*)d_out);
}